// Round 3
// baseline (1200.044 us; speedup 1.0000x reference)
//
#include <hip/hip_runtime.h>

typedef unsigned short UST;
typedef __attribute__((ext_vector_type(8))) __bf16 bf16x8;
typedef __attribute__((ext_vector_type(4))) float f32x4;

__device__ __forceinline__ float bf2f(UST u) {
    union { unsigned int i; float f; } v; v.i = ((unsigned int)u) << 16; return v.f;
}
__device__ __forceinline__ UST f2bf(float f) {
    union { float f; unsigned int i; } v; v.f = f;
    return (UST)((v.i + 0x7fffu + ((v.i >> 16) & 1u)) >> 16);
}

__device__ __forceinline__ void gl2lds16(const UST* g, UST* l) {
    __builtin_amdgcn_global_load_lds(
        (const __attribute__((address_space(1))) unsigned int*)g,
        (__attribute__((address_space(3))) unsigned int*)l, 16, 0, 0);
}

// ---------------------------------------------------------------------------
// Weight prep: W'[o,i] = (qw/15*2-1)*scale + sum_r lb[o,r]*la[r,i], cast bf16.
// qw+scale PREFETCHED into registers before the LoRA FMA loop so the HBM
// latency hides behind ~4000 cyc of VALU work. lb_s padded to stride 33
// (banks (o+r)%32, conflict-free).
// ---------------------------------------------------------------------------
__global__ __launch_bounds__(256) void prep_w(
    const int* __restrict__ qw, const float* __restrict__ scale,
    const float* __restrict__ la, const float* __restrict__ lb,
    UST* __restrict__ wp)
{
    int l = blockIdx.x, ot = blockIdx.y, it = blockIdx.z;
    __shared__ float la_s[32 * 128];    // [r][i]
    __shared__ float lb_s[128 * 33];    // [o][r], +1 pad
    int t = threadIdx.x;
    int o0 = (t >> 4) * 8;
    int i0 = (t & 15) * 8;

    const int* qL = qw + (size_t)l * 1024 * 1024;
    const float* sL = scale + (size_t)l * 1024 * 64;

    // ---- prefetch (stays in flight across staging + FMA loop) ----
    const int* qbase = qL + (size_t)(ot * 128 + o0) * 1024 + it * 128 + i0;
    int4 qv[16];
    #pragma unroll
    for (int a = 0; a < 8; a++) {
        qv[2 * a]     = *(const int4*)(qbase + (size_t)a * 1024);
        qv[2 * a + 1] = *(const int4*)(qbase + (size_t)a * 1024 + 4);
    }
    float sc[8];
    #pragma unroll
    for (int a = 0; a < 8; a++)
        sc[a] = sL[(size_t)(ot * 128 + o0 + a) * 64 + ((it * 128 + i0) >> 4)];

    // ---- stage LoRA factors ----
    const float* laL = la + (size_t)l * 32 * 1024;
    const float* lbL = lb + (size_t)l * 1024 * 32 + (size_t)ot * 128 * 32;
    for (int e = t; e < 32 * 128; e += 256) {
        int r = e >> 7, i = e & 127;
        la_s[e] = laL[r * 1024 + it * 128 + i];
    }
    for (int e = t; e < 128 * 32; e += 256) {
        int o = e >> 5, r = e & 31;
        lb_s[o * 33 + r] = lbL[e];
    }
    __syncthreads();

    float acc[8][8];
    #pragma unroll
    for (int a = 0; a < 8; a++)
        #pragma unroll
        for (int c = 0; c < 8; c++) acc[a][c] = 0.f;
    for (int r = 0; r < 32; ++r) {
        float bv[8], av[8];
        #pragma unroll
        for (int j = 0; j < 8; j++) bv[j] = lb_s[(o0 + j) * 33 + r];
        #pragma unroll
        for (int j = 0; j < 8; j++) av[j] = la_s[r * 128 + i0 + j];
        #pragma unroll
        for (int a = 0; a < 8; a++)
            #pragma unroll
            for (int c = 0; c < 8; c++) acc[a][c] += bv[a] * av[c];
    }

    UST* wL = wp + (size_t)l * 1024 * 1024;
    #pragma unroll
    for (int a = 0; a < 8; a++) {
        int go = ot * 128 + o0 + a;
        int gi = it * 128 + i0;
        float s = sc[a];
        int q[8];
        q[0] = qv[2 * a].x; q[1] = qv[2 * a].y; q[2] = qv[2 * a].z; q[3] = qv[2 * a].w;
        q[4] = qv[2 * a + 1].x; q[5] = qv[2 * a + 1].y; q[6] = qv[2 * a + 1].z; q[7] = qv[2 * a + 1].w;
        UST o8[8];
        #pragma unroll
        for (int c = 0; c < 8; c++) {
            float w = ((float)q[c] * (2.0f / 15.0f) - 1.0f) * s + acc[a][c];
            o8[c] = f2bf(w);
        }
        *(ushort4*)(wL + (size_t)go * 1024 + gi) = make_ushort4(o8[0], o8[1], o8[2], o8[3]);
        *(ushort4*)(wL + (size_t)go * 1024 + gi + 4) = make_ushort4(o8[4], o8[5], o8[6], o8[7]);
    }
}

__global__ __launch_bounds__(256) void f32_to_bf16(const float* __restrict__ x,
                                                   UST* __restrict__ o)
{
    size_t i = ((size_t)blockIdx.x * 256 + threadIdx.x) * 4;
    float4 v = *(const float4*)(x + i);
    *(ushort4*)(o + i) = make_ushort4(f2bf(v.x), f2bf(v.y), f2bf(v.z), f2bf(v.w));
}

// ---------------------------------------------------------------------------
// GEMM: C[M,1024] = X[M,1024] @ W[1024,1024]^T (+bias, epilogue by mode)
//   mode 0: relu, bf16 out     mode 1: bf16 out     mode 2: +resid, fp32 out
// 128x128 tile, BK=32, 4 waves 2x2, mfma 16x16x32 bf16 4x4/wave.
// 3-stage pipeline (48 KB LDS, 3 blocks/CU): s_waitcnt vmcnt(8) keeps two
// tiles of global_load_lds in flight across the barrier (AITER pattern).
// LDS k-chunk XOR swizzle; epilogue transposes through LDS for 16B stores.
// ---------------------------------------------------------------------------
#define BM 128
#define BN 128
#define BK 32

#define WB8 asm volatile("s_waitcnt vmcnt(8)\n\ts_barrier" ::: "memory")
#define WB4 asm volatile("s_waitcnt vmcnt(4)\n\ts_barrier" ::: "memory")
#define WB0 asm volatile("s_waitcnt vmcnt(0)\n\ts_barrier" ::: "memory")
#define LGB asm volatile("s_waitcnt lgkmcnt(0)\n\ts_barrier" ::: "memory")

__global__ __launch_bounds__(256, 3) void gemm_ep(
    const UST* __restrict__ X, const UST* __restrict__ W,
    const float* __restrict__ bias,
    UST* __restrict__ outb, const UST* __restrict__ resid,
    float* __restrict__ outf, int mode)
{
    const int K = 1024;
    __shared__ UST smem[24576];   // 3 stages x (A:4096 + B:4096) UST
    int tid = threadIdx.x;
    int wave = tid >> 6, lane = tid & 63;
    int wm = wave >> 1, wn = wave & 1;
    int bn = blockIdx.x, bm = blockIdx.y;
    int la15 = lane & 15, qa = lane >> 4;

    int c0 = tid, c1 = tid + 256;
    int r0 = c0 >> 2, k0c = ((c0 & 3) ^ ((r0 >> 1) & 3)) * 8;
    int r1 = c1 >> 2, k1c = ((c1 & 3) ^ ((r1 >> 1) & 3)) * 8;
    const UST* gA0 = X + (size_t)(bm * BM + r0) * K + k0c;
    const UST* gA1 = X + (size_t)(bm * BM + r1) * K + k1c;
    const UST* gB0 = W + (size_t)(bn * BN + r0) * K + k0c;
    const UST* gB1 = W + (size_t)(bn * BN + r1) * K + k1c;

    int offA[4], offB[4];
    #pragma unroll
    for (int i = 0; i < 4; i++) {
        int ra = wm * 64 + i * 16 + la15;
        offA[i] = ra * 32 + ((qa ^ ((ra >> 1) & 3)) * 8);
        int rb = wn * 64 + i * 16 + la15;
        offB[i] = rb * 32 + ((qa ^ ((rb >> 1) & 3)) * 8);
    }

    f32x4 acc[4][4];
    #pragma unroll
    for (int i = 0; i < 4; i++)
        #pragma unroll
        for (int j = 0; j < 4; j++) acc[i][j] = (f32x4){0.f, 0.f, 0.f, 0.f};

    auto issue = [&](int kk, int buf) {
        UST* dA = smem + buf * 8192;
        UST* dB = dA + 4096;
        gl2lds16(gA0 + kk, dA + c0 * 8);
        gl2lds16(gA1 + kk, dA + c1 * 8);
        gl2lds16(gB0 + kk, dB + c0 * 8);
        gl2lds16(gB1 + kk, dB + c1 * 8);
    };
    auto compute = [&](int buf) {
        const UST* pA = smem + buf * 8192;
        const UST* pB = pA + 4096;
        bf16x8 af[4], bfr[4];
        #pragma unroll
        for (int mi = 0; mi < 4; mi++) af[mi] = *(const bf16x8*)&pA[offA[mi]];
        #pragma unroll
        for (int ni = 0; ni < 4; ni++) bfr[ni] = *(const bf16x8*)&pB[offB[ni]];
        #pragma unroll
        for (int mi = 0; mi < 4; mi++)
            #pragma unroll
            for (int ni = 0; ni < 4; ni++)
                acc[mi][ni] = __builtin_amdgcn_mfma_f32_16x16x32_bf16(
                    af[mi], bfr[ni], acc[mi][ni], 0, 0, 0);
    };

    issue(0, 0);
    issue(BK, 1);
    #pragma unroll 1
    for (int t = 0; t < 30; t += 3) {
        issue((t + 2) * BK, 2); WB8; compute(0); LGB;
        issue((t + 3) * BK, 0); WB8; compute(1); LGB;
        issue((t + 4) * BK, 1); WB8; compute(2); LGB;
    }
    WB4; compute(0); LGB;   // tile 30 (buf 0)
    WB0; compute(1); LGB;   // tile 31 (buf 1)

    // ---------------- epilogue: 2 half-tiles (64x128 fp32 = 32 KB) ----------
    float* cs = (float*)smem;
    int cc = tid & 15, rw = tid >> 4;
    int gcolb = bn * BN + cc * 8;
    float4 bv0 = *(const float4*)&bias[gcolb];
    float4 bv1 = *(const float4*)&bias[gcolb + 4];

    #pragma unroll
    for (int h = 0; h < 2; ++h) {
        if (wm == h) {
            #pragma unroll
            for (int mi = 0; mi < 4; mi++)
                #pragma unroll
                for (int ni = 0; ni < 4; ni++) {
                    int colx = (wn * 64 + ni * 16 + la15) ^ (qa << 4);
                    #pragma unroll
                    for (int r2 = 0; r2 < 4; r2++) {
                        int rl = mi * 16 + qa * 4 + r2;
                        cs[rl * 128 + colx] = acc[mi][ni][r2];
                    }
                }
        }
        LGB;
        #pragma unroll
        for (int g = 0; g < 4; ++g) {
            int rl = g * 16 + rw;
            int swz = ((rl >> 2) & 3) << 2;
            int gr0 = ((cc * 2) ^ swz) * 4;
            float4 v0 = *(const float4*)&cs[rl * 128 + gr0];
            float4 v1 = *(const float4*)&cs[rl * 128 + gr0 + 4];
            float o0 = v0.x + bv0.x, o1 = v0.y + bv0.y;
            float o2 = v0.z + bv0.z, o3 = v0.w + bv0.w;
            float o4 = v1.x + bv1.x, o5 = v1.y + bv1.y;
            float o6 = v1.z + bv1.z, o7 = v1.w + bv1.w;
            if (mode == 0) {
                o0 = fmaxf(o0, 0.f); o1 = fmaxf(o1, 0.f);
                o2 = fmaxf(o2, 0.f); o3 = fmaxf(o3, 0.f);
                o4 = fmaxf(o4, 0.f); o5 = fmaxf(o5, 0.f);
                o6 = fmaxf(o6, 0.f); o7 = fmaxf(o7, 0.f);
            }
            int grow = bm * BM + h * 64 + rl;
            size_t base = (size_t)grow * 1024 + gcolb;
            if (mode == 2) {
                ushort4 rv0 = *(const ushort4*)&resid[base];
                ushort4 rv1 = *(const ushort4*)&resid[base + 4];
                o0 += bf2f(rv0.x); o1 += bf2f(rv0.y);
                o2 += bf2f(rv0.z); o3 += bf2f(rv0.w);
                o4 += bf2f(rv1.x); o5 += bf2f(rv1.y);
                o6 += bf2f(rv1.z); o7 += bf2f(rv1.w);
                *(float4*)&outf[base] = make_float4(o0, o1, o2, o3);
                *(float4*)&outf[base + 4] = make_float4(o4, o5, o6, o7);
            } else {
                uint4 pk;
                pk.x = (unsigned)f2bf(o0) | ((unsigned)f2bf(o1) << 16);
                pk.y = (unsigned)f2bf(o2) | ((unsigned)f2bf(o3) << 16);
                pk.z = (unsigned)f2bf(o4) | ((unsigned)f2bf(o5) << 16);
                pk.w = (unsigned)f2bf(o6) | ((unsigned)f2bf(o7) << 16);
                *(uint4*)&outb[base] = pk;
            }
        }
        LGB;
    }
}

// ---------------------------------------------------------------------------
// LayerNorm(h3 + r) -> r   (one block per row)
// ---------------------------------------------------------------------------
__global__ __launch_bounds__(256) void ln_res(
    const UST* __restrict__ h3, UST* __restrict__ r,
    const float* __restrict__ g, const float* __restrict__ b)
{
    int row = blockIdx.x;
    int t = threadIdx.x;
    int lane = t & 63, wave = t >> 6;
    const ushort4* hp = (const ushort4*)(h3 + (size_t)row * 1024);
    ushort4* rp = (ushort4*)(r + (size_t)row * 1024);
    ushort4 hv = hp[t], rv = rp[t];
    float u0 = bf2f(hv.x) + bf2f(rv.x);
    float u1 = bf2f(hv.y) + bf2f(rv.y);
    float u2 = bf2f(hv.z) + bf2f(rv.z);
    float u3 = bf2f(hv.w) + bf2f(rv.w);

    float s = u0 + u1 + u2 + u3;
    #pragma unroll
    for (int off = 32; off > 0; off >>= 1) s += __shfl_down(s, off, 64);
    __shared__ float red[8];
    if (lane == 0) red[wave] = s;
    __syncthreads();
    float mean = (red[0] + red[1] + red[2] + red[3]) * (1.0f / 1024.0f);

    float d0 = u0 - mean, d1 = u1 - mean, d2 = u2 - mean, d3 = u3 - mean;
    float vs = d0 * d0 + d1 * d1 + d2 * d2 + d3 * d3;
    #pragma unroll
    for (int off = 32; off > 0; off >>= 1) vs += __shfl_down(vs, off, 64);
    if (lane == 0) red[4 + wave] = vs;
    __syncthreads();
    float var = (red[4] + red[5] + red[6] + red[7]) * (1.0f / 1024.0f);
    float rstd = rsqrtf(var + 1e-5f);

    int i0 = t * 4;
    ushort4 o;
    o.x = f2bf(d0 * rstd * g[i0 + 0] + b[i0 + 0]);
    o.y = f2bf(d1 * rstd * g[i0 + 1] + b[i0 + 1]);
    o.z = f2bf(d2 * rstd * g[i0 + 2] + b[i0 + 2]);
    o.w = f2bf(d3 * rstd * g[i0 + 3] + b[i0 + 3]);
    rp[t] = o;
}

// ---------------------------------------------------------------------------
extern "C" void kernel_launch(void* const* d_in, const int* in_sizes, int n_in,
                              void* d_out, int out_size, void* d_ws, size_t ws_size,
                              hipStream_t stream) {
    const float* x     = (const float*)d_in[0];
    const float* scale = (const float*)d_in[1];
    const float* bias  = (const float*)d_in[2];
    const float* la    = (const float*)d_in[3];
    const float* lb    = (const float*)d_in[4];
    const float* ln_w  = (const float*)d_in[5];
    const float* ln_b  = (const float*)d_in[6];
    const int*   qw    = (const int*)d_in[7];

    const int M = in_sizes[0] / 1024;                  // 16384
    const size_t WPB = (size_t)18 * 1024 * 1024 * 2;
    const size_t ACT = (size_t)M * 1024 * 2;

    UST* wp = (UST*)d_ws;
    UST* A  = (UST*)((char*)d_ws + WPB);            // residual
    UST* Cb = (UST*)((char*)d_ws + WPB + ACT);      // ping
    UST* Bb = (UST*)d_out;                          // pong (dead before fp32 write)

    prep_w<<<dim3(18, 8, 8), 256, 0, stream>>>(qw, scale, la, lb, wp);
    f32_to_bf16<<<(M * 1024) / (256 * 4), 256, 0, stream>>>(x, A);

    int li = 0;
    for (int blk = 0; blk < 6; ++blk) {
        gemm_ep<<<dim3(8, M / 128), 256, 0, stream>>>(
            A, wp + (size_t)li * 1024 * 1024, bias + li * 1024, Bb, nullptr, nullptr, 0);
        li++;
        gemm_ep<<<dim3(8, M / 128), 256, 0, stream>>>(
            Bb, wp + (size_t)li * 1024 * 1024, bias + li * 1024, Cb, nullptr, nullptr, 0);
        li++;
        if (blk < 5) {
            gemm_ep<<<dim3(8, M / 128), 256, 0, stream>>>(
                Cb, wp + (size_t)li * 1024 * 1024, bias + li * 1024, Bb, nullptr, nullptr, 1);
            li++;
            ln_res<<<M, 256, 0, stream>>>(Bb, A, ln_w + blk * 1024, ln_b + blk * 1024);
        } else {
            gemm_ep<<<dim3(8, M / 128), 256, 0, stream>>>(
                Cb, wp + (size_t)li * 1024 * 1024, bias + li * 1024, nullptr, A,
                (float*)d_out, 2);
            li++;
        }
    }
}

// Round 4
// 1097.377 us; speedup vs baseline: 1.0936x; 1.0936x over previous
//
#include <hip/hip_runtime.h>

typedef unsigned short UST;
typedef __attribute__((ext_vector_type(8))) __bf16 bf16x8;
typedef __attribute__((ext_vector_type(4))) float f32x4;

__device__ __forceinline__ float bf2f(UST u) {
    union { unsigned int i; float f; } v; v.i = ((unsigned int)u) << 16; return v.f;
}
__device__ __forceinline__ UST f2bf(float f) {
    union { float f; unsigned int i; } v; v.f = f;
    return (UST)((v.i + 0x7fffu + ((v.i >> 16) & 1u)) >> 16);
}

__device__ __forceinline__ void gl2lds16(const UST* g, UST* l) {
    __builtin_amdgcn_global_load_lds(
        (const __attribute__((address_space(1))) unsigned int*)g,
        (__attribute__((address_space(3))) unsigned int*)l, 16, 0, 0);
}

// ---------------------------------------------------------------------------
// Weight prep: W'[o,i] = (qw/15*2-1)*scale + sum_r lb[o,r]*la[r,i], cast bf16.
// 64x128 tile, 4x8/thread: acc 32 VGPR + 8xint4 prefetch 32 VGPR, LDS 24.8KB
// -> ~5 blocks/CU resident (R3's 16xint4 prefetch halved occupancy; reverted).
// ---------------------------------------------------------------------------
__global__ __launch_bounds__(256) void prep_w(
    const int* __restrict__ qw, const float* __restrict__ scale,
    const float* __restrict__ la, const float* __restrict__ lb,
    UST* __restrict__ wp)
{
    int l = blockIdx.x, ot = blockIdx.y, it = blockIdx.z;   // 18 x 16 x 8
    __shared__ float la_s[32 * 128];    // [r][i] 16KB
    __shared__ float lb_s[64 * 33];     // [o][r] padded, 8.25KB
    int t = threadIdx.x;
    int o0 = (t >> 4) * 4;    // 0..60
    int i0 = (t & 15) * 8;    // 0..120

    // ---- prefetch qw + scales (modest: 8 int4 + 4 floats) ----
    const int* qbase = qw + (size_t)l * 1048576 + (size_t)(ot * 64 + o0) * 1024
                       + it * 128 + i0;
    int4 qv[8];
    #pragma unroll
    for (int a = 0; a < 4; a++) {
        qv[2 * a]     = *(const int4*)(qbase + (size_t)a * 1024);
        qv[2 * a + 1] = *(const int4*)(qbase + (size_t)a * 1024 + 4);
    }
    const float* sL = scale + (size_t)l * 65536;
    float sc[4];
    #pragma unroll
    for (int a = 0; a < 4; a++)
        sc[a] = sL[(size_t)(ot * 64 + o0 + a) * 64 + ((it * 128 + i0) >> 4)];

    // ---- stage LoRA factors ----
    const float* laL = la + (size_t)l * 32768;
    const float* lbL = lb + (size_t)l * 32768 + (size_t)ot * 64 * 32;
    for (int e = t; e < 32 * 128; e += 256) {
        int r = e >> 7, i = e & 127;
        la_s[e] = laL[r * 1024 + it * 128 + i];
    }
    for (int e = t; e < 64 * 32; e += 256) {
        int o = e >> 5, r = e & 31;
        lb_s[o * 33 + r] = lbL[e];
    }
    __syncthreads();

    float acc[4][8];
    #pragma unroll
    for (int a = 0; a < 4; a++)
        #pragma unroll
        for (int c = 0; c < 8; c++) acc[a][c] = 0.f;
    for (int r = 0; r < 32; ++r) {
        float4 av0 = *(const float4*)&la_s[r * 128 + i0];
        float4 av1 = *(const float4*)&la_s[r * 128 + i0 + 4];
        float av[8] = {av0.x, av0.y, av0.z, av0.w, av1.x, av1.y, av1.z, av1.w};
        float bv[4];
        #pragma unroll
        for (int j = 0; j < 4; j++) bv[j] = lb_s[(o0 + j) * 33 + r];
        #pragma unroll
        for (int a = 0; a < 4; a++)
            #pragma unroll
            for (int c = 0; c < 8; c++) acc[a][c] += bv[a] * av[c];
    }

    UST* wL = wp + (size_t)l * 1048576;
    #pragma unroll
    for (int a = 0; a < 4; a++) {
        int go = ot * 64 + o0 + a;
        int gi = it * 128 + i0;
        float s = sc[a];
        int q[8];
        q[0] = qv[2 * a].x; q[1] = qv[2 * a].y; q[2] = qv[2 * a].z; q[3] = qv[2 * a].w;
        q[4] = qv[2 * a + 1].x; q[5] = qv[2 * a + 1].y;
        q[6] = qv[2 * a + 1].z; q[7] = qv[2 * a + 1].w;
        UST o8[8];
        #pragma unroll
        for (int c = 0; c < 8; c++) {
            float w = ((float)q[c] * (2.0f / 15.0f) - 1.0f) * s + acc[a][c];
            o8[c] = f2bf(w);
        }
        *(ushort4*)(wL + (size_t)go * 1024 + gi) = make_ushort4(o8[0], o8[1], o8[2], o8[3]);
        *(ushort4*)(wL + (size_t)go * 1024 + gi + 4) = make_ushort4(o8[4], o8[5], o8[6], o8[7]);
    }
}

__global__ __launch_bounds__(256) void f32_to_bf16(const float* __restrict__ x,
                                                   UST* __restrict__ o)
{
    size_t i = ((size_t)blockIdx.x * 256 + threadIdx.x) * 4;
    float4 v = *(const float4*)(x + i);
    *(ushort4*)(o + i) = make_ushort4(f2bf(v.x), f2bf(v.y), f2bf(v.z), f2bf(v.w));
}

// ---------------------------------------------------------------------------
// GEMM: C[M,1024] = X[M,1024] @ W[1024,1024]^T (+bias, epilogue by mode)
//   mode 0: relu, bf16 out     mode 1: bf16 out     mode 2: +resid, fp32 out
// R2-proven K-loop: 2-stage, 32KB LDS, vmcnt(4), launch_bounds(256,4) ->
// all 1024 blocks co-resident (4/CU) in ONE round (R3's 3-stage/48KB broke
// residency and regressed). 1D grid + XCD swizzle: xcd=bid&7 gets 16 bm x
// all 8 bn -> per-XCD L2 working set ~6MB, X fetched from L3 once (32MB)
// instead of 8x (256MB).
// ---------------------------------------------------------------------------
#define BM 128
#define BN 128
#define BK 32

#define WB4 asm volatile("s_waitcnt vmcnt(4)\n\ts_barrier" ::: "memory")
#define WB0 asm volatile("s_waitcnt vmcnt(0)\n\ts_barrier" ::: "memory")
#define LGB asm volatile("s_waitcnt lgkmcnt(0)\n\ts_barrier" ::: "memory")

__global__ __launch_bounds__(256, 4) void gemm_ep(
    const UST* __restrict__ X, const UST* __restrict__ W,
    const float* __restrict__ bias,
    UST* __restrict__ outb, const UST* __restrict__ resid,
    float* __restrict__ outf, int mode)
{
    const int K = 1024;
    __shared__ UST smem[16384];   // 2 stages x (A:4096 + B:4096) UST
    int tid = threadIdx.x;
    int wave = tid >> 6, lane = tid & 63;
    int wm = wave >> 1, wn = wave & 1;

    // XCD swizzle: per-XCD bm-major over 16 bm tiles, then bn
    int bid = blockIdx.x;
    int nbm8 = gridDim.x >> 6;            // (M/128)/8
    int xcd = bid & 7, idx = bid >> 3;
    int bm = xcd + ((idx % nbm8) << 3);
    int bn = idx / nbm8;

    int la15 = lane & 15, qa = lane >> 4;

    int c0 = tid, c1 = tid + 256;
    int r0 = c0 >> 2, k0c = ((c0 & 3) ^ ((r0 >> 1) & 3)) * 8;
    int r1 = c1 >> 2, k1c = ((c1 & 3) ^ ((r1 >> 1) & 3)) * 8;
    const UST* gA0 = X + (size_t)(bm * BM + r0) * K + k0c;
    const UST* gA1 = X + (size_t)(bm * BM + r1) * K + k1c;
    const UST* gB0 = W + (size_t)(bn * BN + r0) * K + k0c;
    const UST* gB1 = W + (size_t)(bn * BN + r1) * K + k1c;

    int offA[4], offB[4];
    #pragma unroll
    for (int i = 0; i < 4; i++) {
        int ra = wm * 64 + i * 16 + la15;
        offA[i] = ra * 32 + ((qa ^ ((ra >> 1) & 3)) * 8);
        int rb = wn * 64 + i * 16 + la15;
        offB[i] = rb * 32 + ((qa ^ ((rb >> 1) & 3)) * 8);
    }

    f32x4 acc[4][4];
    #pragma unroll
    for (int i = 0; i < 4; i++)
        #pragma unroll
        for (int j = 0; j < 4; j++) acc[i][j] = (f32x4){0.f, 0.f, 0.f, 0.f};

    auto issue = [&](int kk, int buf) {
        UST* dA = smem + buf * 8192;
        UST* dB = dA + 4096;
        gl2lds16(gA0 + kk, dA + c0 * 8);
        gl2lds16(gA1 + kk, dA + c1 * 8);
        gl2lds16(gB0 + kk, dB + c0 * 8);
        gl2lds16(gB1 + kk, dB + c1 * 8);
    };
    auto compute = [&](int buf) {
        const UST* pA = smem + buf * 8192;
        const UST* pB = pA + 4096;
        bf16x8 af[4], bfr[4];
        #pragma unroll
        for (int mi = 0; mi < 4; mi++) af[mi] = *(const bf16x8*)&pA[offA[mi]];
        #pragma unroll
        for (int ni = 0; ni < 4; ni++) bfr[ni] = *(const bf16x8*)&pB[offB[ni]];
        #pragma unroll
        for (int mi = 0; mi < 4; mi++)
            #pragma unroll
            for (int ni = 0; ni < 4; ni++)
                acc[mi][ni] = __builtin_amdgcn_mfma_f32_16x16x32_bf16(
                    af[mi], bfr[ni], acc[mi][ni], 0, 0, 0);
    };

    issue(0, 0);
    #pragma unroll 2
    for (int it = 0; it < 31; ++it) {
        int cur = it & 1;
        issue((it + 1) * BK, cur ^ 1);
        WB4;
        compute(cur);
        LGB;
    }
    WB0;
    compute(1);
    LGB;

    // ---------------- epilogue: 2 half-tiles (64x128 fp32 = 32 KB) ----------
    float* cs = (float*)smem;
    int cc = tid & 15, rw = tid >> 4;
    int gcolb = bn * BN + cc * 8;
    float4 bv0 = *(const float4*)&bias[gcolb];
    float4 bv1 = *(const float4*)&bias[gcolb + 4];

    #pragma unroll
    for (int h = 0; h < 2; ++h) {
        if (wm == h) {
            #pragma unroll
            for (int mi = 0; mi < 4; mi++)
                #pragma unroll
                for (int ni = 0; ni < 4; ni++) {
                    int colx = (wn * 64 + ni * 16 + la15) ^ (qa << 4);
                    #pragma unroll
                    for (int r2 = 0; r2 < 4; r2++) {
                        int rl = mi * 16 + qa * 4 + r2;
                        cs[rl * 128 + colx] = acc[mi][ni][r2];
                    }
                }
        }
        LGB;
        #pragma unroll
        for (int g = 0; g < 4; ++g) {
            int rl = g * 16 + rw;
            int swz = ((rl >> 2) & 3) << 2;
            int gr0 = ((cc * 2) ^ swz) * 4;
            float4 v0 = *(const float4*)&cs[rl * 128 + gr0];
            float4 v1 = *(const float4*)&cs[rl * 128 + gr0 + 4];
            float o0 = v0.x + bv0.x, o1 = v0.y + bv0.y;
            float o2 = v0.z + bv0.z, o3 = v0.w + bv0.w;
            float o4 = v1.x + bv1.x, o5 = v1.y + bv1.y;
            float o6 = v1.z + bv1.z, o7 = v1.w + bv1.w;
            if (mode == 0) {
                o0 = fmaxf(o0, 0.f); o1 = fmaxf(o1, 0.f);
                o2 = fmaxf(o2, 0.f); o3 = fmaxf(o3, 0.f);
                o4 = fmaxf(o4, 0.f); o5 = fmaxf(o5, 0.f);
                o6 = fmaxf(o6, 0.f); o7 = fmaxf(o7, 0.f);
            }
            int grow = bm * BM + h * 64 + rl;
            size_t base = (size_t)grow * 1024 + gcolb;
            if (mode == 2) {
                ushort4 rv0 = *(const ushort4*)&resid[base];
                ushort4 rv1 = *(const ushort4*)&resid[base + 4];
                o0 += bf2f(rv0.x); o1 += bf2f(rv0.y);
                o2 += bf2f(rv0.z); o3 += bf2f(rv0.w);
                o4 += bf2f(rv1.x); o5 += bf2f(rv1.y);
                o6 += bf2f(rv1.z); o7 += bf2f(rv1.w);
                *(float4*)&outf[base] = make_float4(o0, o1, o2, o3);
                *(float4*)&outf[base + 4] = make_float4(o4, o5, o6, o7);
            } else {
                uint4 pk;
                pk.x = (unsigned)f2bf(o0) | ((unsigned)f2bf(o1) << 16);
                pk.y = (unsigned)f2bf(o2) | ((unsigned)f2bf(o3) << 16);
                pk.z = (unsigned)f2bf(o4) | ((unsigned)f2bf(o5) << 16);
                pk.w = (unsigned)f2bf(o6) | ((unsigned)f2bf(o7) << 16);
                *(uint4*)&outb[base] = pk;
            }
        }
        LGB;
    }
}

// ---------------------------------------------------------------------------
// LayerNorm(h3 + r) -> r   (one block per row)
// ---------------------------------------------------------------------------
__global__ __launch_bounds__(256) void ln_res(
    const UST* __restrict__ h3, UST* __restrict__ r,
    const float* __restrict__ g, const float* __restrict__ b)
{
    int row = blockIdx.x;
    int t = threadIdx.x;
    int lane = t & 63, wave = t >> 6;
    const ushort4* hp = (const ushort4*)(h3 + (size_t)row * 1024);
    ushort4* rp = (ushort4*)(r + (size_t)row * 1024);
    ushort4 hv = hp[t], rv = rp[t];
    float u0 = bf2f(hv.x) + bf2f(rv.x);
    float u1 = bf2f(hv.y) + bf2f(rv.y);
    float u2 = bf2f(hv.z) + bf2f(rv.z);
    float u3 = bf2f(hv.w) + bf2f(rv.w);

    float s = u0 + u1 + u2 + u3;
    #pragma unroll
    for (int off = 32; off > 0; off >>= 1) s += __shfl_down(s, off, 64);
    __shared__ float red[8];
    if (lane == 0) red[wave] = s;
    __syncthreads();
    float mean = (red[0] + red[1] + red[2] + red[3]) * (1.0f / 1024.0f);

    float d0 = u0 - mean, d1 = u1 - mean, d2 = u2 - mean, d3 = u3 - mean;
    float vs = d0 * d0 + d1 * d1 + d2 * d2 + d3 * d3;
    #pragma unroll
    for (int off = 32; off > 0; off >>= 1) vs += __shfl_down(vs, off, 64);
    if (lane == 0) red[4 + wave] = vs;
    __syncthreads();
    float var = (red[4] + red[5] + red[6] + red[7]) * (1.0f / 1024.0f);
    float rstd = rsqrtf(var + 1e-5f);

    int i0 = t * 4;
    ushort4 o;
    o.x = f2bf(d0 * rstd * g[i0 + 0] + b[i0 + 0]);
    o.y = f2bf(d1 * rstd * g[i0 + 1] + b[i0 + 1]);
    o.z = f2bf(d2 * rstd * g[i0 + 2] + b[i0 + 2]);
    o.w = f2bf(d3 * rstd * g[i0 + 3] + b[i0 + 3]);
    rp[t] = o;
}

// ---------------------------------------------------------------------------
extern "C" void kernel_launch(void* const* d_in, const int* in_sizes, int n_in,
                              void* d_out, int out_size, void* d_ws, size_t ws_size,
                              hipStream_t stream) {
    const float* x     = (const float*)d_in[0];
    const float* scale = (const float*)d_in[1];
    const float* bias  = (const float*)d_in[2];
    const float* la    = (const float*)d_in[3];
    const float* lb    = (const float*)d_in[4];
    const float* ln_w  = (const float*)d_in[5];
    const float* ln_b  = (const float*)d_in[6];
    const int*   qw    = (const int*)d_in[7];

    const int M = in_sizes[0] / 1024;                  // 16384
    const size_t WPB = (size_t)18 * 1024 * 1024 * 2;
    const size_t ACT = (size_t)M * 1024 * 2;

    UST* wp = (UST*)d_ws;
    UST* A  = (UST*)((char*)d_ws + WPB);            // residual
    UST* Cb = (UST*)((char*)d_ws + WPB + ACT);      // ping
    UST* Bb = (UST*)d_out;                          // pong (dead before fp32 write)

    prep_w<<<dim3(18, 16, 8), 256, 0, stream>>>(qw, scale, la, lb, wp);
    f32_to_bf16<<<(M * 1024) / (256 * 4), 256, 0, stream>>>(x, A);

    int nblk = (M / 128) * 8;
    int li = 0;
    for (int blk = 0; blk < 6; ++blk) {
        gemm_ep<<<nblk, 256, 0, stream>>>(
            A, wp + (size_t)li * 1024 * 1024, bias + li * 1024, Bb, nullptr, nullptr, 0);
        li++;
        gemm_ep<<<nblk, 256, 0, stream>>>(
            Bb, wp + (size_t)li * 1024 * 1024, bias + li * 1024, Cb, nullptr, nullptr, 0);
        li++;
        if (blk < 5) {
            gemm_ep<<<nblk, 256, 0, stream>>>(
                Cb, wp + (size_t)li * 1024 * 1024, bias + li * 1024, Bb, nullptr, nullptr, 1);
            li++;
            ln_res<<<M, 256, 0, stream>>>(Bb, A, ln_w + blk * 1024, ln_b + blk * 1024);
        } else {
            gemm_ep<<<nblk, 256, 0, stream>>>(
                Cb, wp + (size_t)li * 1024 * 1024, bias + li * 1024, nullptr, A,
                (float*)d_out, 2);
            li++;
        }
    }
}

// Round 5
// 953.358 us; speedup vs baseline: 1.2588x; 1.1511x over previous
//
#include <hip/hip_runtime.h>

typedef unsigned short UST;
typedef __attribute__((ext_vector_type(8))) __bf16 bf16x8;
typedef __attribute__((ext_vector_type(4))) float f32x4;

__device__ __forceinline__ float bf2f(UST u) {
    union { unsigned int i; float f; } v; v.i = ((unsigned int)u) << 16; return v.f;
}
__device__ __forceinline__ UST f2bf(float f) {
    union { float f; unsigned int i; } v; v.f = f;
    return (UST)((v.i + 0x7fffu + ((v.i >> 16) & 1u)) >> 16);
}

__device__ __forceinline__ void gl2lds16(const UST* g, UST* l) {
    __builtin_amdgcn_global_load_lds(
        (const __attribute__((address_space(1))) unsigned int*)g,
        (__attribute__((address_space(3))) unsigned int*)l, 16, 0, 0);
}

#define WB4 asm volatile("s_waitcnt vmcnt(4)\n\ts_barrier" ::: "memory")
#define WB0 asm volatile("s_waitcnt vmcnt(0)\n\ts_barrier" ::: "memory")
#define LGB asm volatile("s_waitcnt lgkmcnt(0)\n\ts_barrier" ::: "memory")

// ---------------------------------------------------------------------------
// Weight prep v2: W'[o,i] = (qw/15*2-1)*scale + (lb@la)[o,i], cast bf16.
// lora via MFMA (K=32 = one mfma_16x16x32_bf16 per 16x16 tile) -- kills the
// 900MB LDS-read outer-product that bounded v1. 128x128 tile, 4 waves 2x2.
// Epilogue = R4 gemm's verified LDS-transpose (64x128 fp32 strips).
// ---------------------------------------------------------------------------
__global__ __launch_bounds__(256) void prep_w(
    const int* __restrict__ qw, const float* __restrict__ scale,
    const float* __restrict__ la, const float* __restrict__ lb,
    UST* __restrict__ wp)
{
    int l = blockIdx.x, ot = blockIdx.y, it = blockIdx.z;   // 18 x 8 x 8
    __shared__ float cs[64 * 128];     // 32 KB transpose buffer
    __shared__ float sc_s[128 * 8];    // 4 KB scales [local_o][local_g]
    int t = threadIdx.x;
    int wave = t >> 6, lane = t & 63;
    int wm = wave >> 1, wn = wave & 1;
    int la15 = lane & 15, qa = lane >> 4;

    // ---- stage scales: 1024 floats, coalesced float4 ----
    {
        int e = t * 4;                 // e&7 in {0,4} -> in-row float4
        int o = e >> 3, g = e & 7;
        const float* sb = scale + ((size_t)l * 1024 + ot * 128 + o) * 64 + it * 8 + g;
        *(float4*)&sc_s[e] = *(const float4*)sb;
    }

    // ---- A-frags: lb[o][r] rows (direct global, cvt to bf16) ----
    bf16x8 af[4];
    const float* lbL = lb + ((size_t)l * 1024 + ot * 128 + wm * 64 + la15) * 32 + qa * 8;
    #pragma unroll
    for (int mi = 0; mi < 4; mi++) {
        float4 u0 = *(const float4*)(lbL + mi * 16 * 32);
        float4 u1 = *(const float4*)(lbL + mi * 16 * 32 + 4);
        union { bf16x8 v; UST u[8]; } A;
        A.u[0] = f2bf(u0.x); A.u[1] = f2bf(u0.y); A.u[2] = f2bf(u0.z); A.u[3] = f2bf(u0.w);
        A.u[4] = f2bf(u1.x); A.u[5] = f2bf(u1.y); A.u[6] = f2bf(u1.z); A.u[7] = f2bf(u1.w);
        af[mi] = A.v;
    }

    // ---- B-frags: la^T[i][r] (strided global scalar loads, cvt) ----
    bf16x8 bfr[4];
    const float* laL = la + ((size_t)l * 32 + qa * 8) * 1024 + it * 128 + wn * 64 + la15;
    #pragma unroll
    for (int ni = 0; ni < 4; ni++) {
        union { bf16x8 v; UST u[8]; } B;
        #pragma unroll
        for (int j = 0; j < 8; j++) B.u[j] = f2bf(laL[(size_t)j * 1024 + ni * 16]);
        bfr[ni] = B.v;
    }

    // ---- lora via MFMA ----
    f32x4 acc[4][4];
    #pragma unroll
    for (int mi = 0; mi < 4; mi++)
        #pragma unroll
        for (int ni = 0; ni < 4; ni++) {
            acc[mi][ni] = (f32x4){0.f, 0.f, 0.f, 0.f};
            acc[mi][ni] = __builtin_amdgcn_mfma_f32_16x16x32_bf16(
                af[mi], bfr[ni], acc[mi][ni], 0, 0, 0);
        }

    // ---- prefetch qw in C-layout (64 dwords, 16-lane coalesced) ----
    int qv[4][4][4];
    const int* qL = qw + (size_t)l * 1048576;
    int obase = ot * 128 + wm * 64, ibase = it * 128 + wn * 64;
    #pragma unroll
    for (int mi = 0; mi < 4; mi++)
        #pragma unroll
        for (int ni = 0; ni < 4; ni++)
            #pragma unroll
            for (int r2 = 0; r2 < 4; r2++)
                qv[mi][ni][r2] = qL[(size_t)(obase + mi * 16 + qa * 4 + r2) * 1024
                                    + ibase + ni * 16 + la15];

    __syncthreads();   // sc_s staged

    // ---- epilogue: dequant+combine -> LDS transpose -> coalesced bf16 store --
    int cc = t & 15, rw = t >> 4;
    UST* wL = wp + (size_t)l * 1048576;
    #pragma unroll
    for (int h = 0; h < 2; ++h) {
        if (wm == h) {
            #pragma unroll
            for (int mi = 0; mi < 4; mi++)
                #pragma unroll
                for (int ni = 0; ni < 4; ni++) {
                    int colx = (wn * 64 + ni * 16 + la15) ^ (qa << 4);
                    #pragma unroll
                    for (int r2 = 0; r2 < 4; r2++) {
                        int rl = mi * 16 + qa * 4 + r2;
                        float s = sc_s[(h * 64 + rl) * 8 + wn * 4 + ni];
                        float w = ((float)qv[mi][ni][r2] * (2.0f / 15.0f) - 1.0f) * s
                                  + acc[mi][ni][r2];
                        cs[rl * 128 + colx] = w;
                    }
                }
        }
        LGB;
        #pragma unroll
        for (int g = 0; g < 4; ++g) {
            int rl = g * 16 + rw;
            int swz = ((rl >> 2) & 3) << 2;
            int gr0 = ((cc * 2) ^ swz) * 4;
            float4 v0 = *(const float4*)&cs[rl * 128 + gr0];
            float4 v1 = *(const float4*)&cs[rl * 128 + gr0 + 4];
            uint4 pk;
            pk.x = (unsigned)f2bf(v0.x) | ((unsigned)f2bf(v0.y) << 16);
            pk.y = (unsigned)f2bf(v0.z) | ((unsigned)f2bf(v0.w) << 16);
            pk.z = (unsigned)f2bf(v1.x) | ((unsigned)f2bf(v1.y) << 16);
            pk.w = (unsigned)f2bf(v1.z) | ((unsigned)f2bf(v1.w) << 16);
            *(uint4*)&wL[(size_t)(ot * 128 + h * 64 + rl) * 1024 + it * 128 + cc * 8] = pk;
        }
        LGB;
    }
}

__global__ __launch_bounds__(256) void f32_to_bf16(const float* __restrict__ x,
                                                   UST* __restrict__ o)
{
    size_t i = ((size_t)blockIdx.x * 256 + threadIdx.x) * 4;
    float4 v = *(const float4*)(x + i);
    *(ushort4*)(o + i) = make_ushort4(f2bf(v.x), f2bf(v.y), f2bf(v.z), f2bf(v.w));
}

// ---------------------------------------------------------------------------
// GEMM v2: C[M,1024] = X[M,1024] @ W[1024,1024]^T (+bias, epilogue by mode)
// 256x256 tile, 512 thr (8 waves 4x2, 4x8 mfma/wave): staged L2 traffic
// 512->268 MB/gemm (X x4, W x64) and LDS frag reads halved per FLOP -- the
// two measured co-limiters of the 128x128 version. 2-stage 64KB LDS, WB4.
// Grid 64x4=256 blocks = exactly 1/CU, one round.
// ---------------------------------------------------------------------------
#define BK 32

__global__ __launch_bounds__(512, 2) void gemm_ep(
    const UST* __restrict__ X, const UST* __restrict__ W,
    const float* __restrict__ bias,
    UST* __restrict__ outb, const UST* __restrict__ resid,
    float* __restrict__ outf, int mode)
{
    const int K = 1024;
    __shared__ UST smem[32768];   // 2 stages x (A:8192 + B:8192) UST
    int tid = threadIdx.x;
    int wave = tid >> 6, lane = tid & 63;
    int wm = wave >> 1, wn = wave & 1;         // 4 x 2 waves
    int la15 = lane & 15, qa = lane >> 4;

    int bid = blockIdx.x;
    int xcd = bid & 7, idx = bid >> 3;         // 256 blocks
    int bm = xcd * 8 + (idx & 7);              // 0..63
    int bn = idx >> 3;                         // 0..3

    // staging: 2048 chunks of 16B per stage (A:1024, B:1024); 4 per thread
    int c0 = tid, c1 = tid + 512;
    int r0 = c0 >> 2, k0c = ((c0 & 3) ^ ((r0 >> 1) & 3)) * 8;
    int r1 = c1 >> 2, k1c = ((c1 & 3) ^ ((r1 >> 1) & 3)) * 8;
    const UST* gA0 = X + (size_t)(bm * 256 + r0) * K + k0c;
    const UST* gA1 = X + (size_t)(bm * 256 + r1) * K + k1c;
    const UST* gB0 = W + (size_t)(bn * 256 + r0) * K + k0c;
    const UST* gB1 = W + (size_t)(bn * 256 + r1) * K + k1c;

    int offA[4], offB[8];
    #pragma unroll
    for (int i = 0; i < 4; i++) {
        int ra = wm * 64 + i * 16 + la15;
        offA[i] = ra * 32 + ((qa ^ ((ra >> 1) & 3)) * 8);
    }
    #pragma unroll
    for (int i = 0; i < 8; i++) {
        int rb = wn * 128 + i * 16 + la15;
        offB[i] = rb * 32 + ((qa ^ ((rb >> 1) & 3)) * 8);
    }

    f32x4 acc[4][8];
    #pragma unroll
    for (int i = 0; i < 4; i++)
        #pragma unroll
        for (int j = 0; j < 8; j++) acc[i][j] = (f32x4){0.f, 0.f, 0.f, 0.f};

    auto issue = [&](int kk, int buf) {
        UST* dA = smem + buf * 16384;
        UST* dB = dA + 8192;
        gl2lds16(gA0 + kk, dA + c0 * 8);
        gl2lds16(gA1 + kk, dA + c1 * 8);
        gl2lds16(gB0 + kk, dB + c0 * 8);
        gl2lds16(gB1 + kk, dB + c1 * 8);
    };
    auto compute = [&](int buf) {
        const UST* pA = smem + buf * 16384;
        const UST* pB = pA + 8192;
        bf16x8 af[4], bfr[8];
        #pragma unroll
        for (int mi = 0; mi < 4; mi++) af[mi] = *(const bf16x8*)&pA[offA[mi]];
        #pragma unroll
        for (int ni = 0; ni < 8; ni++) bfr[ni] = *(const bf16x8*)&pB[offB[ni]];
        #pragma unroll
        for (int mi = 0; mi < 4; mi++)
            #pragma unroll
            for (int ni = 0; ni < 8; ni++)
                acc[mi][ni] = __builtin_amdgcn_mfma_f32_16x16x32_bf16(
                    af[mi], bfr[ni], acc[mi][ni], 0, 0, 0);
    };

    issue(0, 0);
    #pragma unroll 2
    for (int it = 0; it < 31; ++it) {
        int cur = it & 1;
        issue((it + 1) * BK, cur ^ 1);
        WB4;
        compute(cur);
        LGB;
    }
    WB0;
    compute(1);
    LGB;

    // -------- epilogue: 4 strips of 64x256 fp32 (64 KB), coalesced out -----
    float* cs = (float*)smem;
    int cc = tid & 31, rw = tid >> 5;
    int gcolb = bn * 256 + cc * 8;
    float4 bv0 = *(const float4*)&bias[gcolb];
    float4 bv1 = *(const float4*)&bias[gcolb + 4];

    #pragma unroll
    for (int h = 0; h < 4; ++h) {
        if (wm == h) {
            #pragma unroll
            for (int mi = 0; mi < 4; mi++)
                #pragma unroll
                for (int ni = 0; ni < 8; ni++) {
                    int colx = (wn * 128 + ni * 16 + la15) ^ (qa << 4);
                    #pragma unroll
                    for (int r2 = 0; r2 < 4; r2++) {
                        int rl = mi * 16 + qa * 4 + r2;
                        cs[rl * 256 + colx] = acc[mi][ni][r2];
                    }
                }
        }
        LGB;
        #pragma unroll
        for (int g = 0; g < 4; ++g) {
            int rl = g * 16 + rw;
            int swz = ((rl >> 2) & 3) << 2;
            int gr0 = ((cc * 2) ^ swz) * 4;
            float4 v0 = *(const float4*)&cs[rl * 256 + gr0];
            float4 v1 = *(const float4*)&cs[rl * 256 + gr0 + 4];
            float o0 = v0.x + bv0.x, o1 = v0.y + bv0.y;
            float o2 = v0.z + bv0.z, o3 = v0.w + bv0.w;
            float o4 = v1.x + bv1.x, o5 = v1.y + bv1.y;
            float o6 = v1.z + bv1.z, o7 = v1.w + bv1.w;
            if (mode == 0) {
                o0 = fmaxf(o0, 0.f); o1 = fmaxf(o1, 0.f);
                o2 = fmaxf(o2, 0.f); o3 = fmaxf(o3, 0.f);
                o4 = fmaxf(o4, 0.f); o5 = fmaxf(o5, 0.f);
                o6 = fmaxf(o6, 0.f); o7 = fmaxf(o7, 0.f);
            }
            int grow = bm * 256 + h * 64 + rl;
            size_t base = (size_t)grow * 1024 + gcolb;
            if (mode == 2) {
                ushort4 rv0 = *(const ushort4*)&resid[base];
                ushort4 rv1 = *(const ushort4*)&resid[base + 4];
                o0 += bf2f(rv0.x); o1 += bf2f(rv0.y);
                o2 += bf2f(rv0.z); o3 += bf2f(rv0.w);
                o4 += bf2f(rv1.x); o5 += bf2f(rv1.y);
                o6 += bf2f(rv1.z); o7 += bf2f(rv1.w);
                *(float4*)&outf[base] = make_float4(o0, o1, o2, o3);
                *(float4*)&outf[base + 4] = make_float4(o4, o5, o6, o7);
            } else {
                uint4 pk;
                pk.x = (unsigned)f2bf(o0) | ((unsigned)f2bf(o1) << 16);
                pk.y = (unsigned)f2bf(o2) | ((unsigned)f2bf(o3) << 16);
                pk.z = (unsigned)f2bf(o4) | ((unsigned)f2bf(o5) << 16);
                pk.w = (unsigned)f2bf(o6) | ((unsigned)f2bf(o7) << 16);
                *(uint4*)&outb[base] = pk;
            }
        }
        LGB;
    }
}

// ---------------------------------------------------------------------------
// LayerNorm(h3 + r) -> r   (one block per row)
// ---------------------------------------------------------------------------
__global__ __launch_bounds__(256) void ln_res(
    const UST* __restrict__ h3, UST* __restrict__ r,
    const float* __restrict__ g, const float* __restrict__ b)
{
    int row = blockIdx.x;
    int t = threadIdx.x;
    int lane = t & 63, wave = t >> 6;
    const ushort4* hp = (const ushort4*)(h3 + (size_t)row * 1024);
    ushort4* rp = (ushort4*)(r + (size_t)row * 1024);
    ushort4 hv = hp[t], rv = rp[t];
    float u0 = bf2f(hv.x) + bf2f(rv.x);
    float u1 = bf2f(hv.y) + bf2f(rv.y);
    float u2 = bf2f(hv.z) + bf2f(rv.z);
    float u3 = bf2f(hv.w) + bf2f(rv.w);

    float s = u0 + u1 + u2 + u3;
    #pragma unroll
    for (int off = 32; off > 0; off >>= 1) s += __shfl_down(s, off, 64);
    __shared__ float red[8];
    if (lane == 0) red[wave] = s;
    __syncthreads();
    float mean = (red[0] + red[1] + red[2] + red[3]) * (1.0f / 1024.0f);

    float d0 = u0 - mean, d1 = u1 - mean, d2 = u2 - mean, d3 = u3 - mean;
    float vs = d0 * d0 + d1 * d1 + d2 * d2 + d3 * d3;
    #pragma unroll
    for (int off = 32; off > 0; off >>= 1) vs += __shfl_down(vs, off, 64);
    if (lane == 0) red[4 + wave] = vs;
    __syncthreads();
    float var = (red[4] + red[5] + red[6] + red[7]) * (1.0f / 1024.0f);
    float rstd = rsqrtf(var + 1e-5f);

    int i0 = t * 4;
    ushort4 o;
    o.x = f2bf(d0 * rstd * g[i0 + 0] + b[i0 + 0]);
    o.y = f2bf(d1 * rstd * g[i0 + 1] + b[i0 + 1]);
    o.z = f2bf(d2 * rstd * g[i0 + 2] + b[i0 + 2]);
    o.w = f2bf(d3 * rstd * g[i0 + 3] + b[i0 + 3]);
    rp[t] = o;
}

// ---------------------------------------------------------------------------
extern "C" void kernel_launch(void* const* d_in, const int* in_sizes, int n_in,
                              void* d_out, int out_size, void* d_ws, size_t ws_size,
                              hipStream_t stream) {
    const float* x     = (const float*)d_in[0];
    const float* scale = (const float*)d_in[1];
    const float* bias  = (const float*)d_in[2];
    const float* la    = (const float*)d_in[3];
    const float* lb    = (const float*)d_in[4];
    const float* ln_w  = (const float*)d_in[5];
    const float* ln_b  = (const float*)d_in[6];
    const int*   qw    = (const int*)d_in[7];

    const int M = in_sizes[0] / 1024;                  // 16384
    const size_t WPB = (size_t)18 * 1024 * 1024 * 2;
    const size_t ACT = (size_t)M * 1024 * 2;

    UST* wp = (UST*)d_ws;
    UST* A  = (UST*)((char*)d_ws + WPB);            // residual
    UST* Cb = (UST*)((char*)d_ws + WPB + ACT);      // ping
    UST* Bb = (UST*)d_out;                          // pong (dead before fp32 write)

    prep_w<<<dim3(18, 8, 8), 256, 0, stream>>>(qw, scale, la, lb, wp);
    f32_to_bf16<<<(M * 1024) / (256 * 4), 256, 0, stream>>>(x, A);

    int nblk = (M / 256) * 4;                          // 256
    int li = 0;
    for (int blk = 0; blk < 6; ++blk) {
        gemm_ep<<<nblk, 512, 0, stream>>>(
            A, wp + (size_t)li * 1024 * 1024, bias + li * 1024, Bb, nullptr, nullptr, 0);
        li++;
        gemm_ep<<<nblk, 512, 0, stream>>>(
            Bb, wp + (size_t)li * 1024 * 1024, bias + li * 1024, Cb, nullptr, nullptr, 0);
        li++;
        if (blk < 5) {
            gemm_ep<<<nblk, 512, 0, stream>>>(
                Cb, wp + (size_t)li * 1024 * 1024, bias + li * 1024, Bb, nullptr, nullptr, 1);
            li++;
            ln_res<<<M, 256, 0, stream>>>(Bb, A, ln_w + blk * 1024, ln_b + blk * 1024);
        } else {
            gemm_ep<<<nblk, 512, 0, stream>>>(
                Cb, wp + (size_t)li * 1024 * 1024, bias + li * 1024, nullptr, A,
                (float*)d_out, 2);
            li++;
        }
    }
}